// Round 6
// baseline (282.732 us; speedup 1.0000x reference)
//
#include <hip/hip_runtime.h>
#include <math.h>

// Problem constants (fixed by reference): B=64, N=512, D=64, H=4, C=64, L=3
// Workspace layout (floats), ws >= 256 MB:
//   xbuf [0 .. 2097152)         : layer activations x (8 MB)
//   hT   [2097152 .. 10485760)  : h TRANSPOSED [head][c][b*512+n] (32 MB)
//   meta [10485760 .. 11534336) : prep metadata (4 MB)
// History: R15 = 266 known-good. R17-R19 mega arc DEAD (grid barrier ~45us
// each). R20 (agg gather coalesce) NEUTRAL. R21 (agg 17->1 syncs, conflict-
// free tables) NEUTRAL -> agg internals are NOT the cost; remaining lever is
// dispatch count.
// R22 (this): fuse lin+prep into ONE kernel, grid 256 = (b,head), 256 thr:
//   - lin tile body VERBATIM, looped 32x (rows b*512..b*512+511); W staged
//     and converted ONCE per block (today: 8x per CU)
//   - next-tile x prefetch into regs (1 block/CU now -> cover load latency)
//   - s/d dots -> LDS sA/dA (kills g_s/g_d global round-trip)
//   - prep body VERBATIM on sA/dA (sort in place, same network, same order)
//   - agg (R21, proven) and readout UNTOUCHED. Dispatches 10 -> 7.
// All arithmetic relocated, not reordered -> absmax must stay 7.629395e-06.
// Decision rule: >=260 -> boundary-overhead theory dead, revert to R21.

using short8  = __attribute__((ext_vector_type(8))) short;
using floatx4 = __attribute__((ext_vector_type(4))) float;

__device__ inline unsigned short f2bf(float f) {
    union { float f; unsigned u; } v; v.f = f;
    unsigned u = v.u + 0x7FFFu + ((v.u >> 16) & 1u);   // round-to-nearest-even
    return (unsigned short)(u >> 16);
}
__device__ inline float bf2f(unsigned short s) {
    union { float f; unsigned u; } v; v.u = ((unsigned)s) << 16;
    return v.f;
}

// ---------------------------------------------------------------------------
// Kernel A+B1 fused: linprep — per (b,head) block: 32x lin tile body + prep.
// ---------------------------------------------------------------------------
__global__ __launch_bounds__(256) void linprep_kernel(const float* __restrict__ x,
                                                      const float* __restrict__ W,
                                                      const float* __restrict__ att_src,
                                                      const float* __restrict__ att_dst,
                                                      float* __restrict__ hT,
                                                      int* __restrict__ g_rank,
                                                      float* __restrict__ g_E1,
                                                      float* __restrict__ g_E2,
                                                      float* __restrict__ g_aZ,
                                                      float* __restrict__ g_bZ,
                                                      int* __restrict__ g_k) {
    __shared__ unsigned short WH[64 * 72], WL[64 * 72];
    __shared__ unsigned short XH[16 * 72], XL[16 * 72];
    __shared__ float sredS[4][16], sredD[4][16];
    __shared__ float sA[512], dA[512];      // s/d dots (then sA sorted in place)
    __shared__ int   s_idxE[512];
    __shared__ float z1suf[513], z2pre[513];
    __shared__ float wred[8];

    const int t  = threadIdx.x;
    const int bh = blockIdx.x;            // b*4 + head (matches meta layout)
    const int b  = bh >> 2;
    const int ct = bh & 3;                // head
    const int c0 = ct * 64;

    // ---- W staging + convert, ONCE per block (verbatim from lin) ----
#pragma unroll
    for (int q = 0; q < 4; ++q) {
        int f = q * 256 + t;
        int wrow = f >> 4, d4 = f & 15;
        float4 v = *(const float4*)(W + (size_t)(c0 + wrow) * 64 + d4 * 4);
        unsigned short h0 = f2bf(v.x), h1 = f2bf(v.y), h2 = f2bf(v.z), h3 = f2bf(v.w);
        ushort4 hi = make_ushort4(h0, h1, h2, h3);
        ushort4 lo = make_ushort4(f2bf(v.x - bf2f(h0)), f2bf(v.y - bf2f(h1)),
                                  f2bf(v.z - bf2f(h2)), f2bf(v.w - bf2f(h3)));
        *(ushort4*)&WH[wrow * 72 + d4 * 4] = hi;
        *(ushort4*)&WL[wrow * 72 + d4 * 4] = lo;
    }
    __syncthreads();

    const int lane = t & 63, wv = t >> 6;
    const int mrow = lane & 15, quad = lane >> 4;
    const int c = wv * 16 + mrow;

    short8 bhf[2], blf[2];
#pragma unroll
    for (int kk = 0; kk < 2; ++kk) {
        int ko = kk * 32 + quad * 8;
        bhf[kk] = *(const short8*)&WH[(wv * 16 + mrow) * 72 + ko];
        blf[kk] = *(const short8*)&WL[(wv * 16 + mrow) * 72 + ko];
    }
    const float as_c = att_src[c0 + c];
    const float ad_c = att_dst[c0 + c];

    // ---- 32 row-tiles of this b (prefetched x loads) ----
    const int xrow = t >> 4, xd4 = t & 15;
    float4 xv = *(const float4*)(x + (size_t)(b * 512 + xrow) * 64 + xd4 * 4);

#pragma unroll 1
    for (int tl = 0; tl < 32; ++tl) {
        const int r0 = b * 512 + tl * 16;   // global row of this tile
        __syncthreads();

        {
            unsigned short h0 = f2bf(xv.x), h1 = f2bf(xv.y), h2 = f2bf(xv.z), h3 = f2bf(xv.w);
            ushort4 hi = make_ushort4(h0, h1, h2, h3);
            ushort4 lo = make_ushort4(f2bf(xv.x - bf2f(h0)), f2bf(xv.y - bf2f(h1)),
                                      f2bf(xv.z - bf2f(h2)), f2bf(xv.w - bf2f(h3)));
            *(ushort4*)&XH[xrow * 72 + xd4 * 4] = hi;
            *(ushort4*)&XL[xrow * 72 + xd4 * 4] = lo;
        }
        // issue next tile's load早 — latency hides under this tile's compute
        if (tl + 1 < 32)
            xv = *(const float4*)(x + (size_t)(r0 + 16 + xrow) * 64 + xd4 * 4);
        __syncthreads();

        short8 ah[2], al[2];
#pragma unroll
        for (int kk = 0; kk < 2; ++kk) {
            int ko = kk * 32 + quad * 8;
            ah[kk] = *(const short8*)&XH[mrow * 72 + ko];
            al[kk] = *(const short8*)&XL[mrow * 72 + ko];
        }

        floatx4 acc = {0.f, 0.f, 0.f, 0.f};
        acc = __builtin_amdgcn_mfma_f32_16x16x32_bf16(ah[0], bhf[0], acc, 0, 0, 0);
        acc = __builtin_amdgcn_mfma_f32_16x16x32_bf16(ah[1], bhf[1], acc, 0, 0, 0);
        acc = __builtin_amdgcn_mfma_f32_16x16x32_bf16(ah[0], blf[0], acc, 0, 0, 0);
        acc = __builtin_amdgcn_mfma_f32_16x16x32_bf16(ah[1], blf[1], acc, 0, 0, 0);
        acc = __builtin_amdgcn_mfma_f32_16x16x32_bf16(al[0], bhf[0], acc, 0, 0, 0);
        acc = __builtin_amdgcn_mfma_f32_16x16x32_bf16(al[1], bhf[1], acc, 0, 0, 0);

        *(float4*)&hT[(size_t)(ct * 64 + c) * 32768 + r0 + quad * 4] =
            make_float4(acc[0], acc[1], acc[2], acc[3]);

        float ps[4], pd[4];
#pragma unroll
        for (int reg = 0; reg < 4; ++reg) { ps[reg] = acc[reg] * as_c; pd[reg] = acc[reg] * ad_c; }
#pragma unroll
        for (int m = 1; m <= 8; m <<= 1) {
#pragma unroll
            for (int reg = 0; reg < 4; ++reg) {
                ps[reg] += __shfl_xor(ps[reg], m, 64);
                pd[reg] += __shfl_xor(pd[reg], m, 64);
            }
        }
        if (mrow < 4) {
            sredS[wv][quad * 4 + mrow] = ps[mrow];
            sredD[wv][quad * 4 + mrow] = pd[mrow];
        }
        __syncthreads();
        if (t < 16) {
            float sS = sredS[0][t] + sredS[1][t] + sredS[2][t] + sredS[3][t];
            float sD = sredD[0][t] + sredD[1][t] + sredD[2][t] + sredD[3][t];
            sA[tl * 16 + t] = sS;           // was g_s[bh*512 + n]
            dA[tl * 16 + t] = sD;           // was g_d[bh*512 + n]
        }
    }
    __syncthreads();

    // ======================= prep body (verbatim, s_val->sA) ================
    const int wid = t >> 6;

    float dreg[2];
    for (int rr = 0; rr < 2; ++rr) dreg[rr] = dA[t + rr * 256];

    float v0 = sA[2 * t], v1 = sA[2 * t + 1];
    int id0 = 2 * t, id1 = 2 * t + 1;
    for (int k = 2; k <= 512; k <<= 1) {
        for (int j = k >> 1; j >= 1; j >>= 1) {
            bool asc = ((t & (k >> 1)) == 0);
            if (j == 1) {
                bool sw = asc ? (v0 > v1) : (v0 < v1);
                if (sw) { float tv = v0; v0 = v1; v1 = tv; int ti = id0; id0 = id1; id1 = ti; }
            } else if (j <= 64) {
                int m = j >> 1;
                float w0 = __shfl_xor(v0, m, 64);
                int  wi0 = __shfl_xor(id0, m, 64);
                float w1 = __shfl_xor(v1, m, 64);
                int  wi1 = __shfl_xor(id1, m, 64);
                bool low = ((t & m) == 0);
                bool wantmin = (low == asc);
                if (wantmin ? (w0 < v0) : (w0 > v0)) { v0 = w0; id0 = wi0; }
                if (wantmin ? (w1 < v1) : (w1 > v1)) { v1 = w1; id1 = wi1; }
            } else {
                int m = j >> 1;
                sA[2 * t] = v0; sA[2 * t + 1] = v1;
                s_idxE[2 * t] = id0; s_idxE[2 * t + 1] = id1;
                __syncthreads();
                int tp = t ^ m;
                float w0 = sA[2 * tp], w1 = sA[2 * tp + 1];
                int wi0 = s_idxE[2 * tp], wi1 = s_idxE[2 * tp + 1];
                bool low = ((t & m) == 0);
                bool wantmin = (low == asc);
                if (wantmin ? (w0 < v0) : (w0 > v0)) { v0 = w0; id0 = wi0; }
                if (wantmin ? (w1 < v1) : (w1 > v1)) { v1 = w1; id1 = wi1; }
                __syncthreads();
            }
        }
    }

    sA[2 * t] = v0; sA[2 * t + 1] = v1;
    __syncthreads();
    const float M = sA[511];
    float e1_0 = __expf(v0 - M), e1_1 = __expf(v1 - M);
    float e2_0 = __expf(0.2f * (v0 - M)), e2_1 = __expf(0.2f * (v1 - M));
    {
        const int base = bh * 512;
        g_E1[base + id0] = e1_0;  g_E1[base + id1] = e1_1;
        g_E2[base + id0] = e2_0;  g_E2[base + id1] = e2_1;
        g_rank[base + id0] = 2 * t;  g_rank[base + id1] = 2 * t + 1;
    }

    float S1 = e1_0 + e1_1, S2 = e2_0 + e2_1;
    float i1 = S1, i2 = S2;
    for (int off = 1; off < 64; off <<= 1) {
        float u1 = __shfl_up(i1, off, 64);
        float u2 = __shfl_up(i2, off, 64);
        if (lane >= off) { i1 += u1; i2 += u2; }
    }
    if (lane == 63) { wred[wid] = i1; wred[4 + wid] = i2; }
    __syncthreads();
    float off1 = 0.f, off2 = 0.f;
    for (int w = 0; w < wid; ++w) { off1 += wred[w]; off2 += wred[4 + w]; }
    const float T1 = wred[0] + wred[1] + wred[2] + wred[3];
    const float T2 = wred[4] + wred[5] + wred[6] + wred[7];
    float pre1 = off1 + i1 - S1;
    float pre2 = off2 + i2 - S2;
    z1suf[2 * t] = T1 - pre1;
    z1suf[2 * t + 1] = T1 - pre1 - e1_0;
    z2pre[2 * t] = pre2;
    z2pre[2 * t + 1] = pre2 + e2_0;
    if (t == 0) { z1suf[512] = 0.f; z2pre[512] = T2; }
    __syncthreads();

    for (int rr = 0; rr < 2; ++rr) {
        int i = t + rr * 256;
        float d = dreg[rr];
        int lo = 0, hi = 512;
        while (lo < hi) {
            int mid = (lo + hi) >> 1;
            if (d + sA[mid] >= 0.f) hi = mid; else lo = mid + 1;
        }
        int k = lo;
        float g = d + M;
        float G = (g >= 0.f) ? g : 0.2f * g;
        float al = __expf(g - G);
        float be = __expf(0.2f * g - G);
        float Z = al * z1suf[k] + be * z2pre[k];
        float inv = 1.0f / Z;
        g_aZ[bh * 512 + i] = al * inv;
        g_bZ[bh * 512 + i] = be * inv;
        g_k[bh * 512 + i]  = k;
    }
}

// ---------------------------------------------------------------------------
// Kernel B2: attn_agg_fin v7 (R21, UNCHANGED — proven bit-identical).
// ---------------------------------------------------------------------------
__global__ __launch_bounds__(256) void attn_agg_fin(const float* __restrict__ hT,
                                                    const int* __restrict__ g_rank,
                                                    const float* __restrict__ g_E1,
                                                    const float* __restrict__ g_E2,
                                                    const float* __restrict__ g_aZ,
                                                    const float* __restrict__ g_bZ,
                                                    const int* __restrict__ g_k,
                                                    const float* __restrict__ bias,
                                                    float* __restrict__ x) {
    const int b  = blockIdx.x & 63;
    const int cg = blockIdx.x >> 6;        // 0..31
    const int c0 = cg * 2;
    const int t = threadIdx.x;
    const int lane = t & 63, wv = t >> 6;  // wv = head 0..3

    __shared__ float A1[4][2][512], A2[4][2][512];
    __shared__ float tots[4][2];

    {
        const int bh = b * 4 + wv;
        const int base = bh * 512;
        const float* hTb = hT + (size_t)(wv * 64 + c0) * 32768 + (size_t)b * 512;
#pragma unroll
        for (int it = 0; it < 8; ++it) {
            int j = it * 64 + lane;
            int rk = g_rank[base + j];
            float e1 = g_E1[base + j];
            float e2 = g_E2[base + j];
            float h0 = hTb[j];
            float h1 = hTb[32768 + j];
            int pk = ((rk & 7) << 6) | (rk >> 3);
            A1[wv][0][pk] = e1 * h0;  A2[wv][0][pk] = e2 * h0;
            A1[wv][1][pk] = e1 * h1;  A2[wv][1][pk] = e2 * h1;
        }
#pragma unroll
        for (int cc = 0; cc < 2; ++cc) {
            float v1[8], v2[8];
#pragma unroll
            for (int i = 0; i < 8; ++i) {
                v1[i] = A1[wv][cc][i * 64 + lane];
                v2[i] = A2[wv][cc][i * 64 + lane];
            }
            float s1 = 0.f, s2 = 0.f;
#pragma unroll
            for (int i = 0; i < 8; ++i) { s1 += v1[i]; s2 += v2[i]; }
            float suf = s1;
#pragma unroll
            for (int off = 1; off < 64; off <<= 1) {
                float u = __shfl_down(suf, off, 64);
                if (lane + off < 64) suf += u;
            }
            float run = suf - s1;
            float pre = s2;
#pragma unroll
            for (int off = 1; off < 64; off <<= 1) {
                float u = __shfl_up(pre, off, 64);
                if (lane >= off) pre += u;
            }
            float run2 = pre - s2;
            if (lane == 63) tots[wv][cc] = pre;
#pragma unroll
            for (int i = 7; i >= 0; --i) { run += v1[i]; v1[i] = run; }
#pragma unroll
            for (int i = 0; i < 8; ++i) { float tv = v2[i]; v2[i] = run2; run2 += tv; }
#pragma unroll
            for (int i = 0; i < 8; ++i) {
                A1[wv][cc][i * 64 + lane] = v1[i];
                A2[wv][cc][i * 64 + lane] = v2[i];
            }
        }
    }
    __syncthreads();

    const float bv0 = bias[c0], bv1 = bias[c0 + 1];
#pragma unroll
    for (int rr = 0; rr < 2; ++rr) {
        const int i = t + rr * 256;
        float a0 = 0.f, a1 = 0.f;
#pragma unroll
        for (int head = 0; head < 4; ++head) {
            const int base = (b * 4 + head) * 512;
            float aZ = g_aZ[base + i];
            float bZ = g_bZ[base + i];
            int k = g_k[base + i];
            if (k < 512) {
                int pk = ((k & 7) << 6) | (k >> 3);
                a0 += aZ * A1[head][0][pk] + bZ * A2[head][0][pk];
                a1 += aZ * A1[head][1][pk] + bZ * A2[head][1][pk];
            } else {
                a0 += bZ * tots[head][0];
                a1 += bZ * tots[head][1];
            }
        }
        float2 o = make_float2(fmaxf(0.25f * a0 + bv0, 0.f),
                               fmaxf(0.25f * a1 + bv1, 0.f));
        *(float2*)&x[(size_t)(b * 512 + i) * 64 + c0] = o;
    }
}

// ---------------------------------------------------------------------------
// Kernel D: readout (unchanged)
// ---------------------------------------------------------------------------
__global__ __launch_bounds__(256) void readout_kernel(const float* __restrict__ x,
                                                      const float* __restrict__ rw,
                                                      const float* __restrict__ rb,
                                                      float* __restrict__ out) {
    __shared__ float red[4][64];
    __shared__ float pooled[64];
    int b = blockIdx.x, t = threadIdx.x;
    int c = t & 63, q = t >> 6;
    float acc = 0.f;
    for (int n = q; n < 512; n += 4) acc += x[((size_t)b * 512 + n) * 64 + c];
    red[q][c] = acc;
    __syncthreads();
    if (t < 64) pooled[t] = (red[0][t] + red[1][t] + red[2][t] + red[3][t]) * (1.0f / 512.0f);
    __syncthreads();
    if (t < 64) {
        float a = rb[t];
        for (int cc = 0; cc < 64; ++cc) a += pooled[cc] * rw[t * 64 + cc];
        out[b * 64 + t] = a;
    }
}

extern "C" void kernel_launch(void* const* d_in, const int* in_sizes, int n_in,
                              void* d_out, int out_size, void* d_ws, size_t ws_size,
                              hipStream_t stream) {
    const float* emb       = (const float*)d_in[0];
    const float* lin_w     = (const float*)d_in[1];
    const float* att_src   = (const float*)d_in[2];
    const float* att_dst   = (const float*)d_in[3];
    const float* conv_b    = (const float*)d_in[4];
    const float* readout_w = (const float*)d_in[5];
    const float* readout_b = (const float*)d_in[6];
    float* out = (float*)d_out;

    float* ws   = (float*)d_ws;
    float* xbuf = ws;                    // 8 MB
    float* hT   = ws + 2097152;          // 32 MB, [head][c][b*512+n]
    float* meta = ws + 10485760;         // 4 MB

    int*   g_rank = (int*)meta;          // inverse rank (by original id)
    float* g_E1   = meta + 131072;       // indexed by ORIGINAL id
    float* g_E2   = meta + 262144;       // indexed by ORIGINAL id
    float* g_aZ   = meta + 393216;
    float* g_bZ   = meta + 524288;
    int*   g_k    = (int*)(meta + 655360);

    for (int l = 0; l < 3; ++l) {
        const float* xin = (l == 0) ? emb : xbuf;
        linprep_kernel<<<256, 256, 0, stream>>>(xin, lin_w + (size_t)l * 16384,
                                                att_src + l * 256, att_dst + l * 256,
                                                hT, g_rank, g_E1, g_E2, g_aZ, g_bZ, g_k);
        attn_agg_fin<<<2048, 256, 0, stream>>>(hT, g_rank, g_E1, g_E2, g_aZ, g_bZ, g_k,
                                               conv_b + l * 64, xbuf);
    }
    readout_kernel<<<64, 256, 0, stream>>>(xbuf, readout_w, readout_b, out);
}

// Round 7
// 237.174 us; speedup vs baseline: 1.1921x; 1.1921x over previous
//
#include <hip/hip_runtime.h>
#include <math.h>

// Problem constants (fixed by reference): B=64, N=512, D=64, H=4, C=64, L=3
// Workspace layout (floats), ws >= 256 MB:
//   xbuf [0 .. 2097152)         : layer activations x (8 MB)
//   hT   [2097152 .. 10485760)  : h TRANSPOSED [head][c][b*512+n] (32 MB)
//   meta [10485760 .. 11534336) : prep metadata (4 MB)
// History: R15/R21 = 266. Mega arc DEAD. R20/R21 agg micro-fixes NEUTRAL.
// R22 fused lin+prep (grid 256): 282.7, but linprep MEASURED = 44.9us at
// 9.3% occupancy / 13% VALU -> latency-bound: 1 wave/SIMD + 3 syncthreads
// per tile x 32 tiles gate every wave on every x-load (~600cy).
// R23 (this): wave-independent lin stage inside the fused kernel:
//   - each wave owns 8 whole tiles (tl = wv, wv+4, ...): NO intra-loop syncs
//     (was 96); A-frags loaded per-lane DIRECT from global x (2xfloat4 per
//     k-chunk, L1/L2-resident) and converted in registers -> XH/XL deleted
//   - wave computes ALL 64 channels (4 c-group W-frags in regs, ~64 VGPR)
//   - s/d dots: in-register group sum then same shfl-xor butterfly; direct
//     sA/dA store (cross-wave sredS reduce deleted)
//   - rolling 1-tile x prefetch per wave
//   - prep body verbatim; agg (R21) + readout untouched
// Numerics: s/d group-sum reordered (fp32) -> absmax may drift to ~2e-5.
// Decision rule: linprep >= 40us or total >= 266 -> revert to R21.

using short8  = __attribute__((ext_vector_type(8))) short;
using floatx4 = __attribute__((ext_vector_type(4))) float;

__device__ inline unsigned short f2bf(float f) {
    union { float f; unsigned u; } v; v.f = f;
    unsigned u = v.u + 0x7FFFu + ((v.u >> 16) & 1u);   // round-to-nearest-even
    return (unsigned short)(u >> 16);
}
__device__ inline float bf2f(unsigned short s) {
    union { float f; unsigned u; } v; v.u = ((unsigned)s) << 16;
    return v.f;
}

// 8 floats (two float4) -> split-bf16 hi/lo short8 fragments, in registers.
__device__ inline void cvt8(const float4 a, const float4 b, short8& hi, short8& lo) {
    float f[8] = {a.x, a.y, a.z, a.w, b.x, b.y, b.z, b.w};
    short8 H, L;
#pragma unroll
    for (int i = 0; i < 8; ++i) {
        unsigned short h = f2bf(f[i]);
        H[i] = (short)h;
        L[i] = (short)f2bf(f[i] - bf2f(h));
    }
    hi = H; lo = L;
}

// ---------------------------------------------------------------------------
// Kernel A+B1 fused: linprep v2 — wave-independent lin + verbatim prep.
// grid 256 = (b,head), 256 threads.
// ---------------------------------------------------------------------------
__global__ __launch_bounds__(256) void linprep_kernel(const float* __restrict__ x,
                                                      const float* __restrict__ W,
                                                      const float* __restrict__ att_src,
                                                      const float* __restrict__ att_dst,
                                                      float* __restrict__ hT,
                                                      int* __restrict__ g_rank,
                                                      float* __restrict__ g_E1,
                                                      float* __restrict__ g_E2,
                                                      float* __restrict__ g_aZ,
                                                      float* __restrict__ g_bZ,
                                                      int* __restrict__ g_k) {
    __shared__ unsigned short WH[64 * 72], WL[64 * 72];
    __shared__ float sA[512], dA[512];      // s/d dots (then sA sorted in place)
    __shared__ int   s_idxE[512];
    __shared__ float z1suf[513], z2pre[513];
    __shared__ float wred[8];

    const int t  = threadIdx.x;
    const int bh = blockIdx.x;            // b*4 + head (matches meta layout)
    const int b  = bh >> 2;
    const int ct = bh & 3;                // head
    const int c0 = ct * 64;

    // ---- W staging + convert, ONCE per block ----
#pragma unroll
    for (int q = 0; q < 4; ++q) {
        int f = q * 256 + t;
        int wrow = f >> 4, d4 = f & 15;
        float4 v = *(const float4*)(W + (size_t)(c0 + wrow) * 64 + d4 * 4);
        unsigned short h0 = f2bf(v.x), h1 = f2bf(v.y), h2 = f2bf(v.z), h3 = f2bf(v.w);
        ushort4 hi = make_ushort4(h0, h1, h2, h3);
        ushort4 lo = make_ushort4(f2bf(v.x - bf2f(h0)), f2bf(v.y - bf2f(h1)),
                                  f2bf(v.z - bf2f(h2)), f2bf(v.w - bf2f(h3)));
        *(ushort4*)&WH[wrow * 72 + d4 * 4] = hi;
        *(ushort4*)&WL[wrow * 72 + d4 * 4] = lo;
    }
    __syncthreads();

    const int lane = t & 63, wv = t >> 6;
    const int mrow = lane & 15, quad = lane >> 4;

    // ---- per-wave W fragments for ALL 4 channel groups ----
    short8 bhf[4][2], blf[4][2];
#pragma unroll
    for (int g = 0; g < 4; ++g)
#pragma unroll
        for (int kk = 0; kk < 2; ++kk) {
            int ko = kk * 32 + quad * 8;
            bhf[g][kk] = *(const short8*)&WH[(g * 16 + mrow) * 72 + ko];
            blf[g][kk] = *(const short8*)&WL[(g * 16 + mrow) * 72 + ko];
        }
    float as_g[4], ad_g[4];
#pragma unroll
    for (int g = 0; g < 4; ++g) {
        as_g[g] = att_src[c0 + g * 16 + mrow];
        ad_g[g] = att_dst[c0 + g * 16 + mrow];
    }

    // ---- wave-independent tile loop: wave wv owns tiles wv, wv+4, ..., wv+28
    // lane reads x[row r0+mrow][cols quad*8 + {0..7, 32..39}] directly.
    const float* xbase = x + (size_t)(b * 512 + mrow) * 64 + quad * 8;
    float4 nxa = *(const float4*)(xbase + (size_t)wv * 1024);
    float4 nxb = *(const float4*)(xbase + (size_t)wv * 1024 + 4);
    float4 nxc = *(const float4*)(xbase + (size_t)wv * 1024 + 32);
    float4 nxd = *(const float4*)(xbase + (size_t)wv * 1024 + 36);

#pragma unroll 1
    for (int tl = wv; tl < 32; tl += 4) {
        float4 xa = nxa, xb = nxb, xc = nxc, xd = nxd;
        if (tl + 4 < 32) {
            const float* nb = xbase + (size_t)(tl + 4) * 1024;
            nxa = *(const float4*)(nb);
            nxb = *(const float4*)(nb + 4);
            nxc = *(const float4*)(nb + 32);
            nxd = *(const float4*)(nb + 36);
        }
        short8 ah0, al0, ah1, al1;
        cvt8(xa, xb, ah0, al0);
        cvt8(xc, xd, ah1, al1);

        floatx4 acc[4];
#pragma unroll
        for (int g = 0; g < 4; ++g) {
            floatx4 a = {0.f, 0.f, 0.f, 0.f};
            a = __builtin_amdgcn_mfma_f32_16x16x32_bf16(ah0, bhf[g][0], a, 0, 0, 0);
            a = __builtin_amdgcn_mfma_f32_16x16x32_bf16(ah1, bhf[g][1], a, 0, 0, 0);
            a = __builtin_amdgcn_mfma_f32_16x16x32_bf16(ah0, blf[g][0], a, 0, 0, 0);
            a = __builtin_amdgcn_mfma_f32_16x16x32_bf16(ah1, blf[g][1], a, 0, 0, 0);
            a = __builtin_amdgcn_mfma_f32_16x16x32_bf16(al0, bhf[g][0], a, 0, 0, 0);
            a = __builtin_amdgcn_mfma_f32_16x16x32_bf16(al1, bhf[g][1], a, 0, 0, 0);
            acc[g] = a;
        }

        const int r0 = b * 512 + tl * 16;
#pragma unroll
        for (int g = 0; g < 4; ++g) {
            *(float4*)&hT[(size_t)(ct * 64 + g * 16 + mrow) * 32768 + r0 + quad * 4] =
                make_float4(acc[g][0], acc[g][1], acc[g][2], acc[g][3]);
        }

        float ps[4], pd[4];
#pragma unroll
        for (int reg = 0; reg < 4; ++reg) {
            ps[reg] = acc[0][reg] * as_g[0] + acc[1][reg] * as_g[1]
                    + acc[2][reg] * as_g[2] + acc[3][reg] * as_g[3];
            pd[reg] = acc[0][reg] * ad_g[0] + acc[1][reg] * ad_g[1]
                    + acc[2][reg] * ad_g[2] + acc[3][reg] * ad_g[3];
        }
#pragma unroll
        for (int m = 1; m <= 8; m <<= 1) {
#pragma unroll
            for (int reg = 0; reg < 4; ++reg) {
                ps[reg] += __shfl_xor(ps[reg], m, 64);
                pd[reg] += __shfl_xor(pd[reg], m, 64);
            }
        }
        if (mrow < 4) {
            sA[tl * 16 + quad * 4 + mrow] = ps[mrow];
            dA[tl * 16 + quad * 4 + mrow] = pd[mrow];
        }
    }
    __syncthreads();

    // ======================= prep body (verbatim) ==========================
    const int wid = t >> 6;

    float dreg[2];
    for (int rr = 0; rr < 2; ++rr) dreg[rr] = dA[t + rr * 256];

    float v0 = sA[2 * t], v1 = sA[2 * t + 1];
    int id0 = 2 * t, id1 = 2 * t + 1;
    for (int k = 2; k <= 512; k <<= 1) {
        for (int j = k >> 1; j >= 1; j >>= 1) {
            bool asc = ((t & (k >> 1)) == 0);
            if (j == 1) {
                bool sw = asc ? (v0 > v1) : (v0 < v1);
                if (sw) { float tv = v0; v0 = v1; v1 = tv; int ti = id0; id0 = id1; id1 = ti; }
            } else if (j <= 64) {
                int m = j >> 1;
                float w0 = __shfl_xor(v0, m, 64);
                int  wi0 = __shfl_xor(id0, m, 64);
                float w1 = __shfl_xor(v1, m, 64);
                int  wi1 = __shfl_xor(id1, m, 64);
                bool low = ((t & m) == 0);
                bool wantmin = (low == asc);
                if (wantmin ? (w0 < v0) : (w0 > v0)) { v0 = w0; id0 = wi0; }
                if (wantmin ? (w1 < v1) : (w1 > v1)) { v1 = w1; id1 = wi1; }
            } else {
                int m = j >> 1;
                sA[2 * t] = v0; sA[2 * t + 1] = v1;
                s_idxE[2 * t] = id0; s_idxE[2 * t + 1] = id1;
                __syncthreads();
                int tp = t ^ m;
                float w0 = sA[2 * tp], w1 = sA[2 * tp + 1];
                int wi0 = s_idxE[2 * tp], wi1 = s_idxE[2 * tp + 1];
                bool low = ((t & m) == 0);
                bool wantmin = (low == asc);
                if (wantmin ? (w0 < v0) : (w0 > v0)) { v0 = w0; id0 = wi0; }
                if (wantmin ? (w1 < v1) : (w1 > v1)) { v1 = w1; id1 = wi1; }
                __syncthreads();
            }
        }
    }

    sA[2 * t] = v0; sA[2 * t + 1] = v1;
    __syncthreads();
    const float M = sA[511];
    float e1_0 = __expf(v0 - M), e1_1 = __expf(v1 - M);
    float e2_0 = __expf(0.2f * (v0 - M)), e2_1 = __expf(0.2f * (v1 - M));
    {
        const int base = bh * 512;
        g_E1[base + id0] = e1_0;  g_E1[base + id1] = e1_1;
        g_E2[base + id0] = e2_0;  g_E2[base + id1] = e2_1;
        g_rank[base + id0] = 2 * t;  g_rank[base + id1] = 2 * t + 1;
    }

    float S1 = e1_0 + e1_1, S2 = e2_0 + e2_1;
    float i1 = S1, i2 = S2;
    for (int off = 1; off < 64; off <<= 1) {
        float u1 = __shfl_up(i1, off, 64);
        float u2 = __shfl_up(i2, off, 64);
        if (lane >= off) { i1 += u1; i2 += u2; }
    }
    if (lane == 63) { wred[wid] = i1; wred[4 + wid] = i2; }
    __syncthreads();
    float off1 = 0.f, off2 = 0.f;
    for (int w = 0; w < wid; ++w) { off1 += wred[w]; off2 += wred[4 + w]; }
    const float T1 = wred[0] + wred[1] + wred[2] + wred[3];
    const float T2 = wred[4] + wred[5] + wred[6] + wred[7];
    float pre1 = off1 + i1 - S1;
    float pre2 = off2 + i2 - S2;
    z1suf[2 * t] = T1 - pre1;
    z1suf[2 * t + 1] = T1 - pre1 - e1_0;
    z2pre[2 * t] = pre2;
    z2pre[2 * t + 1] = pre2 + e2_0;
    if (t == 0) { z1suf[512] = 0.f; z2pre[512] = T2; }
    __syncthreads();

    for (int rr = 0; rr < 2; ++rr) {
        int i = t + rr * 256;
        float d = dreg[rr];
        int lo = 0, hi = 512;
        while (lo < hi) {
            int mid = (lo + hi) >> 1;
            if (d + sA[mid] >= 0.f) hi = mid; else lo = mid + 1;
        }
        int k = lo;
        float g = d + M;
        float G = (g >= 0.f) ? g : 0.2f * g;
        float al = __expf(g - G);
        float be = __expf(0.2f * g - G);
        float Z = al * z1suf[k] + be * z2pre[k];
        float inv = 1.0f / Z;
        g_aZ[bh * 512 + i] = al * inv;
        g_bZ[bh * 512 + i] = be * inv;
        g_k[bh * 512 + i]  = k;
    }
}

// ---------------------------------------------------------------------------
// Kernel B2: attn_agg_fin v7 (R21, UNCHANGED).
// ---------------------------------------------------------------------------
__global__ __launch_bounds__(256) void attn_agg_fin(const float* __restrict__ hT,
                                                    const int* __restrict__ g_rank,
                                                    const float* __restrict__ g_E1,
                                                    const float* __restrict__ g_E2,
                                                    const float* __restrict__ g_aZ,
                                                    const float* __restrict__ g_bZ,
                                                    const int* __restrict__ g_k,
                                                    const float* __restrict__ bias,
                                                    float* __restrict__ x) {
    const int b  = blockIdx.x & 63;
    const int cg = blockIdx.x >> 6;        // 0..31
    const int c0 = cg * 2;
    const int t = threadIdx.x;
    const int lane = t & 63, wv = t >> 6;  // wv = head 0..3

    __shared__ float A1[4][2][512], A2[4][2][512];
    __shared__ float tots[4][2];

    {
        const int bh = b * 4 + wv;
        const int base = bh * 512;
        const float* hTb = hT + (size_t)(wv * 64 + c0) * 32768 + (size_t)b * 512;
#pragma unroll
        for (int it = 0; it < 8; ++it) {
            int j = it * 64 + lane;
            int rk = g_rank[base + j];
            float e1 = g_E1[base + j];
            float e2 = g_E2[base + j];
            float h0 = hTb[j];
            float h1 = hTb[32768 + j];
            int pk = ((rk & 7) << 6) | (rk >> 3);
            A1[wv][0][pk] = e1 * h0;  A2[wv][0][pk] = e2 * h0;
            A1[wv][1][pk] = e1 * h1;  A2[wv][1][pk] = e2 * h1;
        }
#pragma unroll
        for (int cc = 0; cc < 2; ++cc) {
            float v1[8], v2[8];
#pragma unroll
            for (int i = 0; i < 8; ++i) {
                v1[i] = A1[wv][cc][i * 64 + lane];
                v2[i] = A2[wv][cc][i * 64 + lane];
            }
            float s1 = 0.f, s2 = 0.f;
#pragma unroll
            for (int i = 0; i < 8; ++i) { s1 += v1[i]; s2 += v2[i]; }
            float suf = s1;
#pragma unroll
            for (int off = 1; off < 64; off <<= 1) {
                float u = __shfl_down(suf, off, 64);
                if (lane + off < 64) suf += u;
            }
            float run = suf - s1;
            float pre = s2;
#pragma unroll
            for (int off = 1; off < 64; off <<= 1) {
                float u = __shfl_up(pre, off, 64);
                if (lane >= off) pre += u;
            }
            float run2 = pre - s2;
            if (lane == 63) tots[wv][cc] = pre;
#pragma unroll
            for (int i = 7; i >= 0; --i) { run += v1[i]; v1[i] = run; }
#pragma unroll
            for (int i = 0; i < 8; ++i) { float tv = v2[i]; v2[i] = run2; run2 += tv; }
#pragma unroll
            for (int i = 0; i < 8; ++i) {
                A1[wv][cc][i * 64 + lane] = v1[i];
                A2[wv][cc][i * 64 + lane] = v2[i];
            }
        }
    }
    __syncthreads();

    const float bv0 = bias[c0], bv1 = bias[c0 + 1];
#pragma unroll
    for (int rr = 0; rr < 2; ++rr) {
        const int i = t + rr * 256;
        float a0 = 0.f, a1 = 0.f;
#pragma unroll
        for (int head = 0; head < 4; ++head) {
            const int base = (b * 4 + head) * 512;
            float aZ = g_aZ[base + i];
            float bZ = g_bZ[base + i];
            int k = g_k[base + i];
            if (k < 512) {
                int pk = ((k & 7) << 6) | (k >> 3);
                a0 += aZ * A1[head][0][pk] + bZ * A2[head][0][pk];
                a1 += aZ * A1[head][1][pk] + bZ * A2[head][1][pk];
            } else {
                a0 += bZ * tots[head][0];
                a1 += bZ * tots[head][1];
            }
        }
        float2 o = make_float2(fmaxf(0.25f * a0 + bv0, 0.f),
                               fmaxf(0.25f * a1 + bv1, 0.f));
        *(float2*)&x[(size_t)(b * 512 + i) * 64 + c0] = o;
    }
}

// ---------------------------------------------------------------------------
// Kernel D: readout (unchanged)
// ---------------------------------------------------------------------------
__global__ __launch_bounds__(256) void readout_kernel(const float* __restrict__ x,
                                                      const float* __restrict__ rw,
                                                      const float* __restrict__ rb,
                                                      float* __restrict__ out) {
    __shared__ float red[4][64];
    __shared__ float pooled[64];
    int b = blockIdx.x, t = threadIdx.x;
    int c = t & 63, q = t >> 6;
    float acc = 0.f;
    for (int n = q; n < 512; n += 4) acc += x[((size_t)b * 512 + n) * 64 + c];
    red[q][c] = acc;
    __syncthreads();
    if (t < 64) pooled[t] = (red[0][t] + red[1][t] + red[2][t] + red[3][t]) * (1.0f / 512.0f);
    __syncthreads();
    if (t < 64) {
        float a = rb[t];
        for (int cc = 0; cc < 64; ++cc) a += pooled[cc] * rw[t * 64 + cc];
        out[b * 64 + t] = a;
    }
}

extern "C" void kernel_launch(void* const* d_in, const int* in_sizes, int n_in,
                              void* d_out, int out_size, void* d_ws, size_t ws_size,
                              hipStream_t stream) {
    const float* emb       = (const float*)d_in[0];
    const float* lin_w     = (const float*)d_in[1];
    const float* att_src   = (const float*)d_in[2];
    const float* att_dst   = (const float*)d_in[3];
    const float* conv_b    = (const float*)d_in[4];
    const float* readout_w = (const float*)d_in[5];
    const float* readout_b = (const float*)d_in[6];
    float* out = (float*)d_out;

    float* ws   = (float*)d_ws;
    float* xbuf = ws;                    // 8 MB
    float* hT   = ws + 2097152;          // 32 MB, [head][c][b*512+n]
    float* meta = ws + 10485760;         // 4 MB

    int*   g_rank = (int*)meta;          // inverse rank (by original id)
    float* g_E1   = meta + 131072;       // indexed by ORIGINAL id
    float* g_E2   = meta + 262144;       // indexed by ORIGINAL id
    float* g_aZ   = meta + 393216;
    float* g_bZ   = meta + 524288;
    int*   g_k    = (int*)(meta + 655360);

    for (int l = 0; l < 3; ++l) {
        const float* xin = (l == 0) ? emb : xbuf;
        linprep_kernel<<<256, 256, 0, stream>>>(xin, lin_w + (size_t)l * 16384,
                                                att_src + l * 256, att_dst + l * 256,
                                                hT, g_rank, g_E1, g_E2, g_aZ, g_bZ, g_k);
        attn_agg_fin<<<2048, 256, 0, stream>>>(hT, g_rank, g_E1, g_E2, g_aZ, g_bZ, g_k,
                                               conv_b + l * 64, xbuf);
    }
    readout_kernel<<<64, 256, 0, stream>>>(xbuf, readout_w, readout_b, out);
}